// Round 20
// baseline (687.297 us; speedup 1.0000x reference)
//
#include <hip/hip_runtime.h>
#include <stdint.h>

#define T_TOK 4096
#define NE 8
#define HH 1024
#define II 2816
#define HE 1056   // HH + 32 ext (lora-g 8, lora-u 8, zero 16)
#define IEW 2944  // Wtd row stride: II + 128 ext (lora-d 8, zero 120) = 23*128
#define HT 23     // hbuf column tiles (22 data + 1 lora/zero ext)
#define RRK 8
#define NPAIR (T_TOK*2)
#define ROWCAP 10240
#define MT_MAX 40   // 256-row tiles
#define SCAL 2.0f

typedef short v8s __attribute__((ext_vector_type(8)));
typedef float v4f __attribute__((ext_vector_type(4)));

__device__ __forceinline__ unsigned short f2bf(float f){
  union { float f; unsigned u; } c; c.f = f;
  unsigned u = c.u;
  u += 0x7FFFu + ((u >> 16) & 1u);
  return (unsigned short)(u >> 16);
}
__device__ __forceinline__ float bf2f(unsigned short h){
  union { unsigned u; float f; } c; c.u = ((unsigned)h) << 16;
  return c.f;
}
__device__ __forceinline__ void gload16(const void* g, void* l){
  __builtin_amdgcn_global_load_lds(
      (const __attribute__((address_space(1))) unsigned int*)g,
      (__attribute__((address_space(3))) unsigned int*)l, 16, 0, 0);
}
__device__ __forceinline__ void fence_(){ asm volatile("" ::: "memory"); }

// ---------------- routing (256-row tiles) ----------------
__global__ void route_count(const int* __restrict__ sel, int* __restrict__ counts,
                            int* __restrict__ bases, int* __restrict__ tile_e,
                            int* __restrict__ tile_r0){
  __shared__ int c[NE];
  int tid = threadIdx.x;
  if (tid < NE) c[tid] = 0;
  __syncthreads();
  for (int p = tid; p < NPAIR; p += 256) atomicAdd(&c[sel[p]], 1);
  __syncthreads();
  if (tid == 0){
    int b = 0;
    for (int e = 0; e < NE; e++){ counts[e] = c[e]; bases[e] = b; b += ((c[e] + 255) >> 8) << 8; }
    bases[NE] = b;
    int t = 0;
    for (int e = 0; e < NE; e++){
      int nt = (c[e] + 255) >> 8;
      for (int i = 0; i < nt; i++){ tile_e[t] = e; tile_r0[t] = bases[e] + i * 256; t++; }
    }
    for (; t < MT_MAX; t++){ tile_e[t] = -1; tile_r0[t] = 0; }
  }
}

__global__ void route_fill(const int* __restrict__ sel, const float* __restrict__ rw,
                           const int* __restrict__ bases,
                           int* __restrict__ row_token, int* __restrict__ row_expert,
                           float* __restrict__ row_w, int* __restrict__ pair2row){
  int e = blockIdx.x;
  int lane = threadIdx.x;
  if (e == NE){
    for (int idx = bases[NE] + lane; idx < ROWCAP; idx += 64){
      row_token[idx] = -1; row_expert[idx] = 0; row_w[idx] = 0.f;
    }
    return;
  }
  int base = bases[e];
  int cnt = 0;
  for (int chunk = 0; chunk < NPAIR; chunk += 64){
    int p = chunk + lane;
    bool m = (sel[p] == e);
    unsigned long long mask = __ballot(m);
    if (m){
      int pos = __popcll(mask & ((1ull << lane) - 1ull));
      int dst = base + cnt + pos;
      row_token[dst] = p >> 1;
      row_expert[dst] = e;
      row_w[dst] = rw[p];
      pair2row[p] = dst;
    }
    cnt += __popcll(mask);
  }
  int nb = bases[e + 1];
  for (int idx = base + cnt + lane; idx < nb; idx += 64){
    row_token[idx] = -1; row_expert[idx] = e; row_w[idx] = 0.f;
  }
}

// ---------------- 32x64 transpose subtile (256 thr, padded LDS) ----------------
__device__ __forceinline__ void transpose_sub32(const float* __restrict__ W,
                                                unsigned short* __restrict__ Wt,
                                                int K, int N, int KE, int e, int bid,
                                                float (*tile)[65]){
  int tilesK = K >> 5;
  int kt = (bid % tilesK) * 32;
  int nt = (bid / tilesK) * 64;
  int tid = threadIdx.x;
  int r = tid >> 3;
  int c0 = (tid & 7) * 8;
  const float* src = W + (size_t)e * K * N + (size_t)(kt + r) * N + nt + c0;
  float4 v0 = *(const float4*)(src);
  float4 v1 = *(const float4*)(src + 4);
  *(float4*)&tile[r][c0]     = v0;
  *(float4*)&tile[r][c0 + 4] = v1;
  __syncthreads();
  int n = tid >> 2;
  int kc = (tid & 3) * 8;
  union { unsigned short us[8]; uint4 q; } pk;
  #pragma unroll
  for (int j = 0; j < 8; j++) pk.us[j] = f2bf(tile[kc + j][n]);
  unsigned short* dst = Wt + (size_t)e * N * KE + (size_t)(nt + n) * KE + kt + kc;
  *(uint4*)(dst) = pk.q;
}

// block ranges:
//   [0, 11264)       gate transpose  (1408/expert: 32 ktiles x 44 ntiles)
//   [11264, 22528)   up transpose
//   [22528, 33792)   down transpose  (1408/expert: 88 ktiles x 16 ntiles)
//   [33792, 33880)   ext_pair
//   [33880, 33912)   ext_down
__global__ void wprep(const float* __restrict__ gate_proj, const float* __restrict__ up_proj,
                      const float* __restrict__ down_proj,
                      const float* __restrict__ gB, const float* __restrict__ uB,
                      const float* __restrict__ dB,
                      unsigned short* __restrict__ Wtg, unsigned short* __restrict__ Wtu,
                      unsigned short* __restrict__ Wtd){
  __shared__ float tile[32][65];
  int b = blockIdx.x;
  if (b < 11264){
    transpose_sub32(gate_proj, Wtg, HH, II, HE, b / 1408, b % 1408, tile);
  } else if (b < 22528){
    b -= 11264;
    transpose_sub32(up_proj, Wtu, HH, II, HE, b / 1408, b % 1408, tile);
  } else if (b < 33792){
    b -= 22528;
    transpose_sub32(down_proj, Wtd, II, HH, IEW, b / 1408, b % 1408, tile);
  } else if (b < 33880){
    int idx = (b - 33792) * 256 + threadIdx.x;
    if (idx >= NE * II) return;
    int e = idx / II, n = idx % II;
    unsigned short* g = Wtg + ((size_t)e * II + n) * HE + HH;
    unsigned short* u = Wtu + ((size_t)e * II + n) * HE + HH;
    #pragma unroll
    for (int j = 0; j < 8; j++){
      g[j] = f2bf(gB[((size_t)e * RRK + j) * II + n]);
      u[j] = 0;
      g[8 + j] = 0;
      u[8 + j] = f2bf(uB[((size_t)e * RRK + j) * II + n]);
    }
    #pragma unroll
    for (int j = 16; j < 32; j++){ g[j] = 0; u[j] = 0; }
  } else {
    int idx = (b - 33880) * 256 + threadIdx.x;
    if (idx >= NE * HH) return;
    int e = idx / HH, n = idx % HH;
    unsigned short* d = Wtd + ((size_t)e * HH + n) * IEW + II;
    #pragma unroll
    for (int j = 0; j < 8; j++) d[j] = f2bf(dB[((size_t)e * RRK + j) * HH + n]);
    for (int j = 8; j < 128; j++) d[j] = 0;
  }
}

// ---------------- gxa2: 16 rows/block, 1 wave/row, A staged in LDS ----------------
__global__ void gxa2(const float* __restrict__ x, const float* __restrict__ gA,
                     const float* __restrict__ uA, const int* __restrict__ row_token,
                     const int* __restrict__ row_expert, unsigned short* __restrict__ Xg){
  __shared__ float Ag[8][1024];
  __shared__ float Au[8][1024];
  int base = blockIdx.x * 16;
  int e = row_expert[base];
  int tid = threadIdx.x;
  // stage A slices (transpose [1024][8] -> [8][1024]); thread t handles k=t*4..t*4+3
  {
    const float* pg = gA + ((size_t)e * HH + tid * 4) * RRK;
    const float* pu = uA + ((size_t)e * HH + tid * 4) * RRK;
    #pragma unroll
    for (int kk = 0; kk < 4; kk++){
      #pragma unroll
      for (int r = 0; r < 8; r++){
        Ag[r][tid * 4 + kk] = pg[kk * RRK + r];
        Au[r][tid * 4 + kk] = pu[kk * RRK + r];
      }
    }
  }
  __syncthreads();
  int w = tid >> 6, lane = tid & 63;
  for (int rr = 0; rr < 4; rr++){
    int p = base + w * 4 + rr;
    int tok = row_token[p];
    float4 xv[4];
    #pragma unroll
    for (int j = 0; j < 4; j++){
      if (tok >= 0) xv[j] = *(const float4*)(x + (size_t)tok * HH + j * 256 + lane * 4);
      else xv[j] = make_float4(0.f, 0.f, 0.f, 0.f);
    }
    #pragma unroll
    for (int j = 0; j < 4; j++){
      uint2 o;
      o.x = (unsigned)f2bf(xv[j].x) | ((unsigned)f2bf(xv[j].y) << 16);
      o.y = (unsigned)f2bf(xv[j].z) | ((unsigned)f2bf(xv[j].w) << 16);
      *(uint2*)(Xg + (size_t)p * HE + j * 256 + lane * 4) = o;
    }
    float ag[8], au[8];
    #pragma unroll
    for (int r = 0; r < 8; r++){ ag[r] = 0.f; au[r] = 0.f; }
    #pragma unroll
    for (int j = 0; j < 4; j++){
      int k0 = j * 256 + lane * 4;
      float xs0 = xv[j].x, xs1 = xv[j].y, xs2 = xv[j].z, xs3 = xv[j].w;
      #pragma unroll
      for (int r = 0; r < 8; r++){
        float4 av = *(const float4*)&Ag[r][k0];
        ag[r] += xs0 * av.x + xs1 * av.y + xs2 * av.z + xs3 * av.w;
        float4 bv = *(const float4*)&Au[r][k0];
        au[r] += xs0 * bv.x + xs1 * bv.y + xs2 * bv.z + xs3 * bv.w;
      }
    }
    #pragma unroll
    for (int r = 0; r < 8; r++){
      for (int off = 32; off > 0; off >>= 1){
        ag[r] += __shfl_down(ag[r], off);
        au[r] += __shfl_down(au[r], off);
      }
    }
    if (lane == 0){
      unsigned short* ext = Xg + (size_t)p * HE + HH;
      #pragma unroll
      for (int r = 0; r < 8; r++){
        ext[r] = f2bf(SCAL * ag[r]);
        ext[8 + r] = f2bf(SCAL * au[r]);
      }
      #pragma unroll
      for (int r = 16; r < 32; r++) ext[r] = 0;
    }
  }
}

// ---------------- LoRA hA: SCAL*(h@down_A) into hbuf_t tile 22 ----------------
__global__ void ha_kernel(const unsigned short* __restrict__ hbuf, const float* __restrict__ dA,
                          const int* __restrict__ row_expert, unsigned short* __restrict__ hout){
  int p = blockIdx.x; int tid = threadIdx.x;
  int e = row_expert[p];
  float a[8];
  #pragma unroll
  for (int r = 0; r < 8; r++) a[r] = 0.f;
  for (int i = 0; i < 11; i++){
    int k = i * 256 + tid;
    float hv = bf2f(hbuf[(size_t)(k >> 7) * (ROWCAP * 128) + (size_t)p * 128 + (k & 127)]);
    const float* pd = dA + ((size_t)e * II + k) * RRK;
    #pragma unroll
    for (int r = 0; r < 8; r++) a[r] += hv * pd[r];
  }
  __shared__ float red[8][4];
  int lane = tid & 63, wv = tid >> 6;
  #pragma unroll
  for (int r = 0; r < 8; r++){
    float v = a[r];
    for (int off = 32; off > 0; off >>= 1) v += __shfl_down(v, off);
    if (lane == 0) red[r][wv] = v;
  }
  __syncthreads();
  unsigned short* ext = hout + (size_t)22 * (ROWCAP * 128) + (size_t)p * 128;
  if (tid < 8)
    ext[tid] = f2bf(SCAL * (red[tid][0] + red[tid][1] + red[tid][2] + red[tid][3]));
  else if (tid < 128)
    ext[tid] = 0;
}

// ---------------- GEMM1: 256x128 tile, BK=32, 512 thr, 2-buffer counted-vmcnt (R9 exact) ----
__launch_bounds__(512, 2)
__global__ void gemm1_kernel(const unsigned short* __restrict__ Xg,
                             const unsigned short* __restrict__ Wtg,
                             const unsigned short* __restrict__ Wtu,
                             const int* __restrict__ tile_e,
                             const int* __restrict__ tile_r0,
                             unsigned short* __restrict__ hbuf){
  int hw = blockIdx.x;
  int lg = (hw & 7) * 110 + (hw >> 3);   // 880 = 8*110
  int mt = lg / 22;
  int n0 = (lg % 22) * 128;

  int e = tile_e[mt];
  if (e < 0) return;
  int row0 = tile_r0[mt];

  __shared__ unsigned short lds[2][4 * 4096];   // per buf: A 16KB, Bg 8KB, Bu 8KB
  int tid = threadIdx.x;
  int lane = tid & 63;
  int w = tid >> 6;
  int wm = w >> 1;
  int wn = w & 1;
  int g = lane >> 4, r16 = lane & 15;

  const unsigned short* srcA = Xg + (size_t)row0 * HE;
  const unsigned short* srcG = Wtg + ((size_t)e * II + n0) * HE;
  const unsigned short* srcU = Wtu + ((size_t)e * II + n0) * HE;

  v4f accg[4][4], accu[4][4];
  #pragma unroll
  for (int i = 0; i < 4; i++)
    #pragma unroll
    for (int j = 0; j < 4; j++){
      accg[i][j] = (v4f){0.f, 0.f, 0.f, 0.f};
      accu[i][j] = (v4f){0.f, 0.f, 0.f, 0.f};
    }

  int uA0 = tid, uA1 = tid + 512;
  int rA0 = uA0 >> 2, rA1 = uA1 >> 2;
  size_t gA0 = (size_t)rA0 * HE + ((uA0 & 3) ^ ((rA0 >> 1) & 3)) * 8;
  size_t gA1 = (size_t)rA1 * HE + ((uA1 & 3) ^ ((rA1 >> 1) & 3)) * 8;
  int lA0 = (uA0 & ~63) * 8, lA1 = (uA1 & ~63) * 8;
  int rB = tid >> 2;
  size_t gB = (size_t)rB * HE + ((tid & 3) ^ ((rB >> 1) & 3)) * 8;
  int lB = (tid & ~63) * 8;

  const int NT = HE / 32;  // 33

  {
    unsigned short* buf = lds[0];
    gload16(srcA + gA0, buf + lA0);
    gload16(srcA + gA1, buf + lA1);
    gload16(srcG + gB, buf + 8192 + lB);
    gload16(srcU + gB, buf + 12288 + lB);
  }

  for (int t = 0; t < NT; t++){
    if (t + 1 < NT){
      unsigned short* nbuf = lds[(t + 1) & 1];
      int ks = (t + 1) * 32;
      gload16(srcA + gA0 + ks, nbuf + lA0);
      gload16(srcA + gA1 + ks, nbuf + lA1);
      gload16(srcG + gB + ks, nbuf + 8192 + lB);
      gload16(srcU + gB + ks, nbuf + 12288 + lB);
      asm volatile("s_waitcnt vmcnt(4)" ::: "memory");
    } else {
      asm volatile("s_waitcnt vmcnt(0)" ::: "memory");
    }
    __builtin_amdgcn_s_barrier();
    fence_();
    const unsigned short* buf = lds[t & 1];
    v8s a[4], bg[4], bu[4];
    #pragma unroll
    for (int f = 0; f < 4; f++){
      int rowA = wm * 64 + f * 16 + r16;
      int ca = g ^ ((rowA >> 1) & 3);
      a[f] = *(const v8s*)(buf + rowA * 32 + ca * 8);
      int rowB = wn * 64 + f * 16 + r16;
      int cb = g ^ ((rowB >> 1) & 3);
      bg[f] = *(const v8s*)(buf + 8192 + rowB * 32 + cb * 8);
      bu[f] = *(const v8s*)(buf + 12288 + rowB * 32 + cb * 8);
    }
    #pragma unroll
    for (int fm = 0; fm < 4; fm++)
      #pragma unroll
      for (int fn = 0; fn < 4; fn++){
        accg[fm][fn] = __builtin_amdgcn_mfma_f32_16x16x32_bf16(a[fm], bg[fn], accg[fm][fn], 0, 0, 0);
        accu[fm][fn] = __builtin_amdgcn_mfma_f32_16x16x32_bf16(a[fm], bu[fn], accu[fm][fn], 0, 0, 0);
      }
    fence_();
    __builtin_amdgcn_s_barrier();
    fence_();
  }

  // epilogue: silu*up -> 64KB LDS tile [256][128] -> contiguous 64KB stream
  unsigned short* sh = (unsigned short*)lds;
  #pragma unroll
  for (int fm = 0; fm < 4; fm++)
    #pragma unroll
    for (int fn = 0; fn < 4; fn++)
      #pragma unroll
      for (int r = 0; r < 4; r++){
        int lrow = wm * 64 + fm * 16 + g * 4 + r;
        int lcol = wn * 64 + fn * 16 + r16;
        float gg = accg[fm][fn][r];
        float uu = accu[fm][fn][r];
        float hh = (gg / (1.f + __expf(-gg))) * uu;
        int ch = (lcol >> 3) ^ (lrow & 7);
        sh[lrow * 128 + ch * 8 + (lcol & 7)] = f2bf(hh);
      }
  __syncthreads();
  unsigned short* dst = hbuf + ((size_t)(n0 >> 7) * ROWCAP + row0) * 128;
  #pragma unroll
  for (int pass = 0; pass < 8; pass++){
    int idx2 = pass * 512 + tid;
    int row = idx2 >> 4;
    int ch = idx2 & 15;
    int chs = ch ^ (row & 7);
    v8s val = *(const v8s*)(sh + row * 128 + chs * 8);
    *(v8s*)(dst + row * 128 + ch * 8) = val;
  }
}

// ---------------- GEMM2: 256x256 tile, K-split 4, BK=32, 512 thr, bf16 partials ----
__launch_bounds__(512, 2)
__global__ void gemm2_kernel(const unsigned short* __restrict__ hbuf,
                             const unsigned short* __restrict__ Wtd,
                             const int* __restrict__ tile_e,
                             const int* __restrict__ tile_r0,
                             const float* __restrict__ row_w,
                             unsigned short* __restrict__ Y4){
  int hw = blockIdx.x;
  int lg = (hw & 7) * 80 + (hw >> 3);    // 640 = 8*80; XCD k owns lg [80k,80k+80)
  int mt = lg / 16;                      // 5 mts per XCD
  int rem = lg % 16;
  int n0 = (rem >> 2) * 256;
  int q = rem & 3;

  int e = tile_e[mt];
  if (e < 0) return;
  int row0 = tile_r0[mt];

  __shared__ unsigned short lds[2][2 * 8192];   // per buf: A 16KB, B 16KB
  int tid = threadIdx.x;
  int lane = tid & 63;
  int w = tid >> 6;
  int wm = w >> 1;     // 0..3: 64-row slices of 256
  int wn = w & 1;      // 0..1: 128-col slices of 256
  int g = lane >> 4, r16 = lane & 15;

  const unsigned short* srcA = hbuf + (size_t)row0 * 128;
  const unsigned short* srcB = Wtd + ((size_t)e * HH + n0) * IEW;

  v4f acc[4][8];
  #pragma unroll
  for (int i = 0; i < 4; i++)
    #pragma unroll
    for (int j = 0; j < 8; j++) acc[i][j] = (v4f){0.f, 0.f, 0.f, 0.f};

  int u0 = tid, u1 = tid + 512;
  int r0_ = u0 >> 2, r1_ = u1 >> 2;
  int c0_ = (u0 & 3) ^ ((r0_ >> 1) & 3), c1_ = (u1 & 3) ^ ((r1_ >> 1) & 3);
  size_t aoff0 = (size_t)r0_ * 128 + c0_ * 8;
  size_t aoff1 = (size_t)r1_ * 128 + c1_ * 8;
  size_t boff0 = (size_t)r0_ * IEW + c0_ * 8;
  size_t boff1 = (size_t)r1_ * IEW + c1_ * 8;
  int l0 = (u0 & ~63) * 8, l1 = (u1 & ~63) * 8;

  const int NQ = (IEW / 32) / 4;         // 23 K-steps per quarter
  int tbeg = q * NQ;
  int tend = tbeg + NQ;

  auto stage = [&](int t, unsigned short* buf){
    int ks = t * 32;
    size_t abase = (size_t)(ks >> 7) * (ROWCAP * 128) + (ks & 127);
    gload16(srcA + abase + aoff0, buf + l0);
    gload16(srcA + abase + aoff1, buf + l1);
    gload16(srcB + (size_t)ks + boff0, buf + 8192 + l0);
    gload16(srcB + (size_t)ks + boff1, buf + 8192 + l1);
  };

  stage(tbeg, lds[tbeg & 1]);

  for (int t = tbeg; t < tend; t++){
    if (t + 1 < tend){
      stage(t + 1, lds[(t + 1) & 1]);
      asm volatile("s_waitcnt vmcnt(4)" ::: "memory");
    } else {
      asm volatile("s_waitcnt vmcnt(0)" ::: "memory");
    }
    __builtin_amdgcn_s_barrier();
    fence_();
    const unsigned short* buf = lds[t & 1];
    v8s a[4], b[8];
    #pragma unroll
    for (int f = 0; f < 4; f++){
      int rowA = wm * 64 + f * 16 + r16;
      int ca = g ^ ((rowA >> 1) & 3);
      a[f] = *(const v8s*)(buf + rowA * 32 + ca * 8);
    }
    #pragma unroll
    for (int fn = 0; fn < 8; fn++){
      int rowB = wn * 128 + fn * 16 + r16;
      int cb = g ^ ((rowB >> 1) & 3);
      b[fn] = *(const v8s*)(buf + 8192 + rowB * 32 + cb * 8);
    }
    #pragma unroll
    for (int fm = 0; fm < 4; fm++)
      #pragma unroll
      for (int fn = 0; fn < 8; fn++)
        acc[fm][fn] = __builtin_amdgcn_mfma_f32_16x16x32_bf16(a[fm], b[fn], acc[fm][fn], 0, 0, 0);
    fence_();
    __builtin_amdgcn_s_barrier();
    fence_();
  }

  unsigned short* Yh = Y4 + (size_t)q * ROWCAP * HH;
  #pragma unroll
  for (int fm = 0; fm < 4; fm++){
    #pragma unroll
    for (int r = 0; r < 4; r++){
      int lrow = wm * 64 + fm * 16 + g * 4 + r;
      int grow = row0 + lrow;
      float wgt = row_w[grow];
      #pragma unroll
      for (int fn = 0; fn < 8; fn++){
        int lcol = wn * 128 + fn * 16 + r16;
        Yh[(size_t)grow * HH + n0 + lcol] = f2bf(wgt * acc[fm][fn][r]);
      }
    }
  }
}

// ---------------- combine: out[t] = sum over 4 quarters of Y4[q][r0]+Y4[q][r1] ----------------
__global__ void combine_kernel(const unsigned short* __restrict__ Y4,
                               const int* __restrict__ pair2row,
                               float* __restrict__ out){
  int t = blockIdx.x;
  int c = threadIdx.x * 4;
  int r0 = pair2row[2 * t];
  int r1 = pair2row[2 * t + 1];
  float s0 = 0.f, s1 = 0.f, s2 = 0.f, s3 = 0.f;
  #pragma unroll
  for (int q = 0; q < 4; q++){
    const unsigned short* Yh = Y4 + (size_t)q * ROWCAP * HH;
    uint2 a = *(const uint2*)(Yh + (size_t)r0 * HH + c);
    uint2 b = *(const uint2*)(Yh + (size_t)r1 * HH + c);
    s0 += bf2f((unsigned short)(a.x & 0xffff)) + bf2f((unsigned short)(b.x & 0xffff));
    s1 += bf2f((unsigned short)(a.x >> 16))    + bf2f((unsigned short)(b.x >> 16));
    s2 += bf2f((unsigned short)(a.y & 0xffff)) + bf2f((unsigned short)(b.y & 0xffff));
    s3 += bf2f((unsigned short)(a.y >> 16))    + bf2f((unsigned short)(b.y >> 16));
  }
  *(float4*)(out + (size_t)t * HH + c) = make_float4(s0, s1, s2, s3);
}

extern "C" void kernel_launch(void* const* d_in, const int* in_sizes, int n_in,
                              void* d_out, int out_size, void* d_ws, size_t ws_size,
                              hipStream_t stream){
  const float* x         = (const float*)d_in[0];
  const float* rw        = (const float*)d_in[1];
  const int*   sel       = (const int*)d_in[2];
  const float* gate_proj = (const float*)d_in[3];
  const float* up_proj   = (const float*)d_in[4];
  const float* down_proj = (const float*)d_in[5];
  const float* gate_A    = (const float*)d_in[6];
  const float* gate_B    = (const float*)d_in[7];
  const float* up_A      = (const float*)d_in[8];
  const float* up_B      = (const float*)d_in[9];
  const float* down_A    = (const float*)d_in[10];
  const float* down_B    = (const float*)d_in[11];
  float* out = (float*)d_out;
  char* ws = (char*)d_ws;

  constexpr size_t OFF_COUNTS = 0;
  constexpr size_t OFF_BASES  = 256;
  constexpr size_t OFF_TILE_E = 512;
  constexpr size_t OFF_TILE_R0 = 1024;
  constexpr size_t OFF_ROWTOK = 2048;
  constexpr size_t OFF_ROWEXP = OFF_ROWTOK + (size_t)ROWCAP * 4;
  constexpr size_t OFF_ROWW   = OFF_ROWEXP + (size_t)ROWCAP * 4;
  constexpr size_t OFF_P2R    = OFF_ROWW + (size_t)ROWCAP * 4;
  constexpr size_t OFF_XG     = OFF_P2R + (size_t)NPAIR * 4;
  constexpr size_t OFF_H      = OFF_XG + (size_t)ROWCAP * HE * 2;
  constexpr size_t OFF_WTG    = OFF_H + (size_t)HT * ROWCAP * 128 * 2;
  constexpr size_t OFF_WTU    = OFF_WTG + (size_t)NE * II * HE * 2;
  constexpr size_t OFF_WTD    = OFF_WTU + (size_t)NE * II * HE * 2;
  constexpr size_t OFF_Y      = OFF_WTG;   // overlay: Wtg+Wtu dead after gemm1 (Y4 bf16 = 84MB < 95MB)

  int* counts    = (int*)(ws + OFF_COUNTS);
  int* bases     = (int*)(ws + OFF_BASES);
  int* tile_e    = (int*)(ws + OFF_TILE_E);
  int* tile_r0   = (int*)(ws + OFF_TILE_R0);
  int* row_token = (int*)(ws + OFF_ROWTOK);
  int* row_expert= (int*)(ws + OFF_ROWEXP);
  float* row_w   = (float*)(ws + OFF_ROWW);
  int* pair2row  = (int*)(ws + OFF_P2R);
  unsigned short* Xg   = (unsigned short*)(ws + OFF_XG);
  unsigned short* hbuf = (unsigned short*)(ws + OFF_H);
  unsigned short* Wtg  = (unsigned short*)(ws + OFF_WTG);
  unsigned short* Wtu  = (unsigned short*)(ws + OFF_WTU);
  unsigned short* Wtd  = (unsigned short*)(ws + OFF_WTD);
  unsigned short* Y4 = (unsigned short*)(ws + OFF_Y);

  route_count<<<1, 256, 0, stream>>>(sel, counts, bases, tile_e, tile_r0);
  route_fill<<<NE + 1, 64, 0, stream>>>(sel, rw, bases, row_token, row_expert, row_w, pair2row);
  wprep<<<33912, 256, 0, stream>>>(gate_proj, up_proj, down_proj, gate_B, up_B, down_B,
                                   Wtg, Wtu, Wtd);
  gxa2<<<ROWCAP / 16, 256, 0, stream>>>(x, gate_A, up_A, row_token, row_expert, Xg);
  gemm1_kernel<<<MT_MAX * (II / 128), 512, 0, stream>>>(Xg, Wtg, Wtu, tile_e, tile_r0, hbuf);
  ha_kernel<<<ROWCAP, 256, 0, stream>>>(hbuf, down_A, row_expert, hbuf);
  gemm2_kernel<<<MT_MAX * (HH / 256) * 4, 512, 0, stream>>>(hbuf, Wtd, tile_e, tile_r0, row_w, Y4);
  combine_kernel<<<T_TOK, 256, 0, stream>>>(Y4, pair2row, out);
}

// Round 21
// 515.788 us; speedup vs baseline: 1.3325x; 1.3325x over previous
//
#include <hip/hip_runtime.h>
#include <stdint.h>

#define T_TOK 4096
#define NE 8
#define HH 1024
#define II 2816
#define HE 1056   // HH + 32 ext (lora-g 8, lora-u 8, zero 16)
#define IEW 2944  // Wtd row stride: II + 128 ext (lora-d 8, zero 120) = 23*128
#define HT 23     // hbuf column tiles (22 data + 1 lora/zero ext)
#define RRK 8
#define NPAIR (T_TOK*2)
#define ROWCAP 10240
#define MT_MAX 40   // 256-row tiles
#define SCAL 2.0f

typedef short v8s __attribute__((ext_vector_type(8)));
typedef float v4f __attribute__((ext_vector_type(4)));

__device__ __forceinline__ unsigned short f2bf(float f){
  union { float f; unsigned u; } c; c.f = f;
  unsigned u = c.u;
  u += 0x7FFFu + ((u >> 16) & 1u);
  return (unsigned short)(u >> 16);
}
__device__ __forceinline__ float bf2f(unsigned short h){
  union { unsigned u; float f; } c; c.u = ((unsigned)h) << 16;
  return c.f;
}
__device__ __forceinline__ void gload16(const void* g, void* l){
  __builtin_amdgcn_global_load_lds(
      (const __attribute__((address_space(1))) unsigned int*)g,
      (__attribute__((address_space(3))) unsigned int*)l, 16, 0, 0);
}
__device__ __forceinline__ void fence_(){ asm volatile("" ::: "memory"); }

// ---------------- routing (256-row tiles) ----------------
__global__ void route_count(const int* __restrict__ sel, int* __restrict__ counts,
                            int* __restrict__ bases, int* __restrict__ tile_e,
                            int* __restrict__ tile_r0){
  __shared__ int c[NE];
  int tid = threadIdx.x;
  if (tid < NE) c[tid] = 0;
  __syncthreads();
  for (int p = tid; p < NPAIR; p += 256) atomicAdd(&c[sel[p]], 1);
  __syncthreads();
  if (tid == 0){
    int b = 0;
    for (int e = 0; e < NE; e++){ counts[e] = c[e]; bases[e] = b; b += ((c[e] + 255) >> 8) << 8; }
    bases[NE] = b;
    int t = 0;
    for (int e = 0; e < NE; e++){
      int nt = (c[e] + 255) >> 8;
      for (int i = 0; i < nt; i++){ tile_e[t] = e; tile_r0[t] = bases[e] + i * 256; t++; }
    }
    for (; t < MT_MAX; t++){ tile_e[t] = -1; tile_r0[t] = 0; }
  }
}

__global__ void route_fill(const int* __restrict__ sel, const float* __restrict__ rw,
                           const int* __restrict__ bases,
                           int* __restrict__ row_token, int* __restrict__ row_expert,
                           float* __restrict__ row_w, int* __restrict__ pair2row){
  int e = blockIdx.x;
  int lane = threadIdx.x;
  if (e == NE){
    for (int idx = bases[NE] + lane; idx < ROWCAP; idx += 64){
      row_token[idx] = -1; row_expert[idx] = 0; row_w[idx] = 0.f;
    }
    return;
  }
  int base = bases[e];
  int cnt = 0;
  for (int chunk = 0; chunk < NPAIR; chunk += 64){
    int p = chunk + lane;
    bool m = (sel[p] == e);
    unsigned long long mask = __ballot(m);
    if (m){
      int pos = __popcll(mask & ((1ull << lane) - 1ull));
      int dst = base + cnt + pos;
      row_token[dst] = p >> 1;
      row_expert[dst] = e;
      row_w[dst] = rw[p];
      pair2row[p] = dst;
    }
    cnt += __popcll(mask);
  }
  int nb = bases[e + 1];
  for (int idx = base + cnt + lane; idx < nb; idx += 64){
    row_token[idx] = -1; row_expert[idx] = e; row_w[idx] = 0.f;
  }
}

// ---------------- pipelined transpose via global_load_lds + counted vmcnt ----------------
// 128k x 64n band per block = 4 subtiles of 32x64 fp32; linear LDS, dbuf, vmcnt(2).
__device__ __forceinline__ void transpose_glds(const float* __restrict__ W,
                                               unsigned short* __restrict__ Wt,
                                               int K, int N, int KE, int e, int bid,
                                               float* lds){   // 2 * 2048 floats
  int tilesK = K >> 7;
  int kt0 = (bid % tilesK) * 128;
  int nt  = (bid / tilesK) * 64;
  int tid = threadIdx.x;   // 256
  const float* base = W + (size_t)e * K * N + nt;
  int u0 = tid, u1 = tid + 256;
  int r0 = u0 >> 4, c0 = (u0 & 15) * 4;
  int r1 = u1 >> 4, c1 = (u1 & 15) * 4;
  int l0 = (u0 & ~63) * 4, l1 = (u1 & ~63) * 4;
  int n = tid >> 2, kc = (tid & 3) * 8;

  auto stage = [&](int s, float* buf){
    gload16(base + (size_t)(kt0 + s * 32 + r0) * N + c0, buf + l0);
    gload16(base + (size_t)(kt0 + s * 32 + r1) * N + c1, buf + l1);
  };

  uint4 outq[4];
  stage(0, lds);
  #pragma unroll
  for (int s = 0; s < 4; s++){
    if (s < 3){
      stage(s + 1, lds + ((s + 1) & 1) * 2048);
      asm volatile("s_waitcnt vmcnt(2)" ::: "memory");
    } else {
      asm volatile("s_waitcnt vmcnt(0)" ::: "memory");
    }
    __builtin_amdgcn_s_barrier();
    fence_();
    const float* buf = lds + (s & 1) * 2048;
    union { unsigned short us[8]; uint4 q; } pk;
    #pragma unroll
    for (int j = 0; j < 8; j++) pk.us[j] = f2bf(buf[(kc + j) * 64 + n]);
    outq[s] = pk.q;
    asm volatile("s_waitcnt lgkmcnt(0)" ::: "memory");
    __builtin_amdgcn_s_barrier();
    fence_();
  }
  unsigned short* dst = Wt + (size_t)e * N * KE + (size_t)(nt + n) * KE + kt0 + kc;
  #pragma unroll
  for (int s = 0; s < 4; s++) *(uint4*)(dst + s * 32) = outq[s];
}

// block ranges:
//   [0, 2816)            gate transpose  (352/expert: 8 kbands x 44 ntiles)
//   [2816, 5632)         up transpose
//   [5632, 8448)         down transpose  (352/expert: 22 kbands x 16 ntiles)
//   [8448, 8536)         ext_pair  (88 blocks over NE*II)
//   [8536, 8568)         ext_down  (32 blocks over NE*HH)
//   [8568, 8568+ROWCAP)  gather + lora-xA
__global__ void wprep(const float* __restrict__ gate_proj, const float* __restrict__ up_proj,
                      const float* __restrict__ down_proj,
                      const float* __restrict__ gB, const float* __restrict__ uB,
                      const float* __restrict__ dB,
                      unsigned short* __restrict__ Wtg, unsigned short* __restrict__ Wtu,
                      unsigned short* __restrict__ Wtd,
                      const float* __restrict__ x, const float* __restrict__ gA,
                      const float* __restrict__ uA, const int* __restrict__ row_token,
                      const int* __restrict__ row_expert, unsigned short* __restrict__ Xg){
  __shared__ float lds[2 * 2048];
  int b = blockIdx.x;
  if (b < 2816){
    transpose_glds(gate_proj, Wtg, HH, II, HE, b / 352, b % 352, lds);
  } else if (b < 5632){
    b -= 2816;
    transpose_glds(up_proj, Wtu, HH, II, HE, b / 352, b % 352, lds);
  } else if (b < 8448){
    b -= 5632;
    transpose_glds(down_proj, Wtd, II, HH, IEW, b / 352, b % 352, lds);
  } else if (b < 8536){
    int idx = (b - 8448) * 256 + threadIdx.x;
    if (idx >= NE * II) return;
    int e = idx / II, n = idx % II;
    unsigned short* g = Wtg + ((size_t)e * II + n) * HE + HH;
    unsigned short* u = Wtu + ((size_t)e * II + n) * HE + HH;
    #pragma unroll
    for (int j = 0; j < 8; j++){
      g[j] = f2bf(gB[((size_t)e * RRK + j) * II + n]);
      u[j] = 0;
      g[8 + j] = 0;
      u[8 + j] = f2bf(uB[((size_t)e * RRK + j) * II + n]);
    }
    #pragma unroll
    for (int j = 16; j < 32; j++){ g[j] = 0; u[j] = 0; }
  } else if (b < 8568){
    int idx = (b - 8536) * 256 + threadIdx.x;
    if (idx >= NE * HH) return;
    int e = idx / HH, n = idx % HH;
    unsigned short* d = Wtd + ((size_t)e * HH + n) * IEW + II;
    #pragma unroll
    for (int j = 0; j < 8; j++) d[j] = f2bf(dB[((size_t)e * RRK + j) * HH + n]);
    for (int j = 8; j < 128; j++) d[j] = 0;
  } else {
    // gather + lora-xA for padded row p
    int p = b - 8568;
    int tid = threadIdx.x;
    int tok = row_token[p]; int e = row_expert[p];
    int k0 = tid * 4;
    float4 xv = make_float4(0.f, 0.f, 0.f, 0.f);
    if (tok >= 0) xv = *(const float4*)(x + (size_t)tok * HH + k0);
    uint2 o;
    o.x = (unsigned)f2bf(xv.x) | ((unsigned)f2bf(xv.y) << 16);
    o.y = (unsigned)f2bf(xv.z) | ((unsigned)f2bf(xv.w) << 16);
    *(uint2*)(Xg + (size_t)p * HE + k0) = o;

    float ag[8], au[8];
    #pragma unroll
    for (int r = 0; r < 8; r++){ ag[r] = 0.f; au[r] = 0.f; }
    if (tok >= 0){
      const float* pg = gA + ((size_t)e * HH + k0) * RRK;
      const float* pu = uA + ((size_t)e * HH + k0) * RRK;
      float xs[4] = {xv.x, xv.y, xv.z, xv.w};
      #pragma unroll
      for (int j = 0; j < 4; j++){
        #pragma unroll
        for (int r = 0; r < 8; r++){
          ag[r] += xs[j] * pg[j * RRK + r];
          au[r] += xs[j] * pu[j * RRK + r];
        }
      }
    }
    __shared__ float redg[8][4], redu[8][4];
    int lane = tid & 63, wv = tid >> 6;
    #pragma unroll
    for (int r = 0; r < 8; r++){
      float v1 = ag[r], v2 = au[r];
      for (int off = 32; off > 0; off >>= 1){ v1 += __shfl_down(v1, off); v2 += __shfl_down(v2, off); }
      if (lane == 0){ redg[r][wv] = v1; redu[r][wv] = v2; }
    }
    __syncthreads();
    if (tid < 8)
      Xg[(size_t)p * HE + HH + tid] = f2bf(SCAL * (redg[tid][0] + redg[tid][1] + redg[tid][2] + redg[tid][3]));
    else if (tid < 16){
      int r = tid - 8;
      Xg[(size_t)p * HE + HH + 8 + r] = f2bf(SCAL * (redu[r][0] + redu[r][1] + redu[r][2] + redu[r][3]));
    } else if (tid < 32){
      Xg[(size_t)p * HE + HH + tid] = 0;
    }
  }
}

// ---------------- LoRA hA: SCAL*(h@down_A) into hbuf_t tile 22 ----------------
__global__ void ha_kernel(const unsigned short* __restrict__ hbuf, const float* __restrict__ dA,
                          const int* __restrict__ row_expert, unsigned short* __restrict__ hout){
  int p = blockIdx.x; int tid = threadIdx.x;
  int e = row_expert[p];
  float a[8];
  #pragma unroll
  for (int r = 0; r < 8; r++) a[r] = 0.f;
  for (int i = 0; i < 11; i++){
    int k = i * 256 + tid;
    float hv = bf2f(hbuf[(size_t)(k >> 7) * (ROWCAP * 128) + (size_t)p * 128 + (k & 127)]);
    const float* pd = dA + ((size_t)e * II + k) * RRK;
    #pragma unroll
    for (int r = 0; r < 8; r++) a[r] += hv * pd[r];
  }
  __shared__ float red[8][4];
  int lane = tid & 63, wv = tid >> 6;
  #pragma unroll
  for (int r = 0; r < 8; r++){
    float v = a[r];
    for (int off = 32; off > 0; off >>= 1) v += __shfl_down(v, off);
    if (lane == 0) red[r][wv] = v;
  }
  __syncthreads();
  unsigned short* ext = hout + (size_t)22 * (ROWCAP * 128) + (size_t)p * 128;
  if (tid < 8)
    ext[tid] = f2bf(SCAL * (red[tid][0] + red[tid][1] + red[tid][2] + red[tid][3]));
  else if (tid < 128)
    ext[tid] = 0;
}

// ---------------- GEMM1: 256x128 tile, BK=32, 512 thr, 2-buffer counted-vmcnt (R9 exact) ----
__launch_bounds__(512, 2)
__global__ void gemm1_kernel(const unsigned short* __restrict__ Xg,
                             const unsigned short* __restrict__ Wtg,
                             const unsigned short* __restrict__ Wtu,
                             const int* __restrict__ tile_e,
                             const int* __restrict__ tile_r0,
                             unsigned short* __restrict__ hbuf){
  int hw = blockIdx.x;
  int lg = (hw & 7) * 110 + (hw >> 3);   // 880 = 8*110
  int mt = lg / 22;
  int n0 = (lg % 22) * 128;

  int e = tile_e[mt];
  if (e < 0) return;
  int row0 = tile_r0[mt];

  __shared__ unsigned short lds[2][4 * 4096];   // per buf: A 16KB, Bg 8KB, Bu 8KB
  int tid = threadIdx.x;
  int lane = tid & 63;
  int w = tid >> 6;
  int wm = w >> 1;
  int wn = w & 1;
  int g = lane >> 4, r16 = lane & 15;

  const unsigned short* srcA = Xg + (size_t)row0 * HE;
  const unsigned short* srcG = Wtg + ((size_t)e * II + n0) * HE;
  const unsigned short* srcU = Wtu + ((size_t)e * II + n0) * HE;

  v4f accg[4][4], accu[4][4];
  #pragma unroll
  for (int i = 0; i < 4; i++)
    #pragma unroll
    for (int j = 0; j < 4; j++){
      accg[i][j] = (v4f){0.f, 0.f, 0.f, 0.f};
      accu[i][j] = (v4f){0.f, 0.f, 0.f, 0.f};
    }

  int uA0 = tid, uA1 = tid + 512;
  int rA0 = uA0 >> 2, rA1 = uA1 >> 2;
  size_t gA0 = (size_t)rA0 * HE + ((uA0 & 3) ^ ((rA0 >> 1) & 3)) * 8;
  size_t gA1 = (size_t)rA1 * HE + ((uA1 & 3) ^ ((rA1 >> 1) & 3)) * 8;
  int lA0 = (uA0 & ~63) * 8, lA1 = (uA1 & ~63) * 8;
  int rB = tid >> 2;
  size_t gB = (size_t)rB * HE + ((tid & 3) ^ ((rB >> 1) & 3)) * 8;
  int lB = (tid & ~63) * 8;

  const int NT = HE / 32;  // 33

  {
    unsigned short* buf = lds[0];
    gload16(srcA + gA0, buf + lA0);
    gload16(srcA + gA1, buf + lA1);
    gload16(srcG + gB, buf + 8192 + lB);
    gload16(srcU + gB, buf + 12288 + lB);
  }

  for (int t = 0; t < NT; t++){
    if (t + 1 < NT){
      unsigned short* nbuf = lds[(t + 1) & 1];
      int ks = (t + 1) * 32;
      gload16(srcA + gA0 + ks, nbuf + lA0);
      gload16(srcA + gA1 + ks, nbuf + lA1);
      gload16(srcG + gB + ks, nbuf + 8192 + lB);
      gload16(srcU + gB + ks, nbuf + 12288 + lB);
      asm volatile("s_waitcnt vmcnt(4)" ::: "memory");
    } else {
      asm volatile("s_waitcnt vmcnt(0)" ::: "memory");
    }
    __builtin_amdgcn_s_barrier();
    fence_();
    const unsigned short* buf = lds[t & 1];
    v8s a[4], bg[4], bu[4];
    #pragma unroll
    for (int f = 0; f < 4; f++){
      int rowA = wm * 64 + f * 16 + r16;
      int ca = g ^ ((rowA >> 1) & 3);
      a[f] = *(const v8s*)(buf + rowA * 32 + ca * 8);
      int rowB = wn * 64 + f * 16 + r16;
      int cb = g ^ ((rowB >> 1) & 3);
      bg[f] = *(const v8s*)(buf + 8192 + rowB * 32 + cb * 8);
      bu[f] = *(const v8s*)(buf + 12288 + rowB * 32 + cb * 8);
    }
    #pragma unroll
    for (int fm = 0; fm < 4; fm++)
      #pragma unroll
      for (int fn = 0; fn < 4; fn++){
        accg[fm][fn] = __builtin_amdgcn_mfma_f32_16x16x32_bf16(a[fm], bg[fn], accg[fm][fn], 0, 0, 0);
        accu[fm][fn] = __builtin_amdgcn_mfma_f32_16x16x32_bf16(a[fm], bu[fn], accu[fm][fn], 0, 0, 0);
      }
    fence_();
    __builtin_amdgcn_s_barrier();
    fence_();
  }

  // epilogue: silu*up -> 64KB LDS tile [256][128] -> contiguous 64KB stream
  unsigned short* sh = (unsigned short*)lds;
  #pragma unroll
  for (int fm = 0; fm < 4; fm++)
    #pragma unroll
    for (int fn = 0; fn < 4; fn++)
      #pragma unroll
      for (int r = 0; r < 4; r++){
        int lrow = wm * 64 + fm * 16 + g * 4 + r;
        int lcol = wn * 64 + fn * 16 + r16;
        float gg = accg[fm][fn][r];
        float uu = accu[fm][fn][r];
        float hh = (gg / (1.f + __expf(-gg))) * uu;
        int ch = (lcol >> 3) ^ (lrow & 7);
        sh[lrow * 128 + ch * 8 + (lcol & 7)] = f2bf(hh);
      }
  __syncthreads();
  unsigned short* dst = hbuf + ((size_t)(n0 >> 7) * ROWCAP + row0) * 128;
  #pragma unroll
  for (int pass = 0; pass < 8; pass++){
    int idx2 = pass * 512 + tid;
    int row = idx2 >> 4;
    int ch = idx2 & 15;
    int chs = ch ^ (row & 7);
    v8s val = *(const v8s*)(sh + row * 128 + chs * 8);
    *(v8s*)(dst + row * 128 + ch * 8) = val;
  }
}

// ---------------- GEMM2: 256x256 tile, K-split 4, BK=32, 512 thr, bf16 partials ----
__launch_bounds__(512, 2)
__global__ void gemm2_kernel(const unsigned short* __restrict__ hbuf,
                             const unsigned short* __restrict__ Wtd,
                             const int* __restrict__ tile_e,
                             const int* __restrict__ tile_r0,
                             const float* __restrict__ row_w,
                             unsigned short* __restrict__ Y4){
  int hw = blockIdx.x;
  int lg = (hw & 7) * 80 + (hw >> 3);    // 640 = 8*80; XCD k owns lg [80k,80k+80)
  int mt = lg / 16;                      // 5 mts per XCD
  int rem = lg % 16;
  int n0 = (rem >> 2) * 256;
  int q = rem & 3;

  int e = tile_e[mt];
  if (e < 0) return;
  int row0 = tile_r0[mt];

  __shared__ unsigned short lds[2][2 * 8192];   // per buf: A 16KB, B 16KB
  int tid = threadIdx.x;
  int lane = tid & 63;
  int w = tid >> 6;
  int wm = w >> 1;     // 0..3: 64-row slices of 256
  int wn = w & 1;      // 0..1: 128-col slices of 256
  int g = lane >> 4, r16 = lane & 15;

  const unsigned short* srcA = hbuf + (size_t)row0 * 128;
  const unsigned short* srcB = Wtd + ((size_t)e * HH + n0) * IEW;

  v4f acc[4][8];
  #pragma unroll
  for (int i = 0; i < 4; i++)
    #pragma unroll
    for (int j = 0; j < 8; j++) acc[i][j] = (v4f){0.f, 0.f, 0.f, 0.f};

  int u0 = tid, u1 = tid + 512;
  int r0_ = u0 >> 2, r1_ = u1 >> 2;
  int c0_ = (u0 & 3) ^ ((r0_ >> 1) & 3), c1_ = (u1 & 3) ^ ((r1_ >> 1) & 3);
  size_t aoff0 = (size_t)r0_ * 128 + c0_ * 8;
  size_t aoff1 = (size_t)r1_ * 128 + c1_ * 8;
  size_t boff0 = (size_t)r0_ * IEW + c0_ * 8;
  size_t boff1 = (size_t)r1_ * IEW + c1_ * 8;
  int l0 = (u0 & ~63) * 8, l1 = (u1 & ~63) * 8;

  const int NQ = (IEW / 32) / 4;         // 23 K-steps per quarter
  int tbeg = q * NQ;
  int tend = tbeg + NQ;

  auto stage = [&](int t, unsigned short* buf){
    int ks = t * 32;
    size_t abase = (size_t)(ks >> 7) * (ROWCAP * 128) + (ks & 127);
    gload16(srcA + abase + aoff0, buf + l0);
    gload16(srcA + abase + aoff1, buf + l1);
    gload16(srcB + (size_t)ks + boff0, buf + 8192 + l0);
    gload16(srcB + (size_t)ks + boff1, buf + 8192 + l1);
  };

  stage(tbeg, lds[tbeg & 1]);

  for (int t = tbeg; t < tend; t++){
    if (t + 1 < tend){
      stage(t + 1, lds[(t + 1) & 1]);
      asm volatile("s_waitcnt vmcnt(4)" ::: "memory");
    } else {
      asm volatile("s_waitcnt vmcnt(0)" ::: "memory");
    }
    __builtin_amdgcn_s_barrier();
    fence_();
    const unsigned short* buf = lds[t & 1];
    v8s a[4], b[8];
    #pragma unroll
    for (int f = 0; f < 4; f++){
      int rowA = wm * 64 + f * 16 + r16;
      int ca = g ^ ((rowA >> 1) & 3);
      a[f] = *(const v8s*)(buf + rowA * 32 + ca * 8);
    }
    #pragma unroll
    for (int fn = 0; fn < 8; fn++){
      int rowB = wn * 128 + fn * 16 + r16;
      int cb = g ^ ((rowB >> 1) & 3);
      b[fn] = *(const v8s*)(buf + 8192 + rowB * 32 + cb * 8);
    }
    #pragma unroll
    for (int fm = 0; fm < 4; fm++)
      #pragma unroll
      for (int fn = 0; fn < 8; fn++)
        acc[fm][fn] = __builtin_amdgcn_mfma_f32_16x16x32_bf16(a[fm], b[fn], acc[fm][fn], 0, 0, 0);
    fence_();
    __builtin_amdgcn_s_barrier();
    fence_();
  }

  unsigned short* Yh = Y4 + (size_t)q * ROWCAP * HH;
  #pragma unroll
  for (int fm = 0; fm < 4; fm++){
    #pragma unroll
    for (int r = 0; r < 4; r++){
      int lrow = wm * 64 + fm * 16 + g * 4 + r;
      int grow = row0 + lrow;
      float wgt = row_w[grow];
      #pragma unroll
      for (int fn = 0; fn < 8; fn++){
        int lcol = wn * 128 + fn * 16 + r16;
        Yh[(size_t)grow * HH + n0 + lcol] = f2bf(wgt * acc[fm][fn][r]);
      }
    }
  }
}

// ---------------- combine: out[t] = sum over 4 quarters of Y4[q][r0]+Y4[q][r1] ----------------
__global__ void combine_kernel(const unsigned short* __restrict__ Y4,
                               const int* __restrict__ pair2row,
                               float* __restrict__ out){
  int t = blockIdx.x;
  int c = threadIdx.x * 4;
  int r0 = pair2row[2 * t];
  int r1 = pair2row[2 * t + 1];
  float s0 = 0.f, s1 = 0.f, s2 = 0.f, s3 = 0.f;
  #pragma unroll
  for (int q = 0; q < 4; q++){
    const unsigned short* Yh = Y4 + (size_t)q * ROWCAP * HH;
    uint2 a = *(const uint2*)(Yh + (size_t)r0 * HH + c);
    uint2 b = *(const uint2*)(Yh + (size_t)r1 * HH + c);
    s0 += bf2f((unsigned short)(a.x & 0xffff)) + bf2f((unsigned short)(b.x & 0xffff));
    s1 += bf2f((unsigned short)(a.x >> 16))    + bf2f((unsigned short)(b.x >> 16));
    s2 += bf2f((unsigned short)(a.y & 0xffff)) + bf2f((unsigned short)(b.y & 0xffff));
    s3 += bf2f((unsigned short)(a.y >> 16))    + bf2f((unsigned short)(b.y >> 16));
  }
  *(float4*)(out + (size_t)t * HH + c) = make_float4(s0, s1, s2, s3);
}

extern "C" void kernel_launch(void* const* d_in, const int* in_sizes, int n_in,
                              void* d_out, int out_size, void* d_ws, size_t ws_size,
                              hipStream_t stream){
  const float* x         = (const float*)d_in[0];
  const float* rw        = (const float*)d_in[1];
  const int*   sel       = (const int*)d_in[2];
  const float* gate_proj = (const float*)d_in[3];
  const float* up_proj   = (const float*)d_in[4];
  const float* down_proj = (const float*)d_in[5];
  const float* gate_A    = (const float*)d_in[6];
  const float* gate_B    = (const float*)d_in[7];
  const float* up_A      = (const float*)d_in[8];
  const float* up_B      = (const float*)d_in[9];
  const float* down_A    = (const float*)d_in[10];
  const float* down_B    = (const float*)d_in[11];
  float* out = (float*)d_out;
  char* ws = (char*)d_ws;

  constexpr size_t OFF_COUNTS = 0;
  constexpr size_t OFF_BASES  = 256;
  constexpr size_t OFF_TILE_E = 512;
  constexpr size_t OFF_TILE_R0 = 1024;
  constexpr size_t OFF_ROWTOK = 2048;
  constexpr size_t OFF_ROWEXP = OFF_ROWTOK + (size_t)ROWCAP * 4;
  constexpr size_t OFF_ROWW   = OFF_ROWEXP + (size_t)ROWCAP * 4;
  constexpr size_t OFF_P2R    = OFF_ROWW + (size_t)ROWCAP * 4;
  constexpr size_t OFF_XG     = OFF_P2R + (size_t)NPAIR * 4;
  constexpr size_t OFF_H      = OFF_XG + (size_t)ROWCAP * HE * 2;
  constexpr size_t OFF_WTG    = OFF_H + (size_t)HT * ROWCAP * 128 * 2;
  constexpr size_t OFF_WTU    = OFF_WTG + (size_t)NE * II * HE * 2;
  constexpr size_t OFF_WTD    = OFF_WTU + (size_t)NE * II * HE * 2;
  constexpr size_t OFF_Y      = OFF_WTG;   // overlay: Wtg+Wtu dead after gemm1 (Y4 bf16 = 84MB < 95MB)

  int* counts    = (int*)(ws + OFF_COUNTS);
  int* bases     = (int*)(ws + OFF_BASES);
  int* tile_e    = (int*)(ws + OFF_TILE_E);
  int* tile_r0   = (int*)(ws + OFF_TILE_R0);
  int* row_token = (int*)(ws + OFF_ROWTOK);
  int* row_expert= (int*)(ws + OFF_ROWEXP);
  float* row_w   = (float*)(ws + OFF_ROWW);
  int* pair2row  = (int*)(ws + OFF_P2R);
  unsigned short* Xg   = (unsigned short*)(ws + OFF_XG);
  unsigned short* hbuf = (unsigned short*)(ws + OFF_H);
  unsigned short* Wtg  = (unsigned short*)(ws + OFF_WTG);
  unsigned short* Wtu  = (unsigned short*)(ws + OFF_WTU);
  unsigned short* Wtd  = (unsigned short*)(ws + OFF_WTD);
  unsigned short* Y4 = (unsigned short*)(ws + OFF_Y);

  route_count<<<1, 256, 0, stream>>>(sel, counts, bases, tile_e, tile_r0);
  route_fill<<<NE + 1, 64, 0, stream>>>(sel, rw, bases, row_token, row_expert, row_w, pair2row);
  wprep<<<8568 + ROWCAP, 256, 0, stream>>>(gate_proj, up_proj, down_proj, gate_B, up_B, down_B,
                                           Wtg, Wtu, Wtd, x, gate_A, up_A,
                                           row_token, row_expert, Xg);
  gemm1_kernel<<<MT_MAX * (II / 128), 512, 0, stream>>>(Xg, Wtg, Wtu, tile_e, tile_r0, hbuf);
  ha_kernel<<<ROWCAP, 256, 0, stream>>>(hbuf, down_A, row_expert, hbuf);
  gemm2_kernel<<<MT_MAX * (HH / 256) * 4, 512, 0, stream>>>(hbuf, Wtd, tile_e, tile_r0, row_w, Y4);
  combine_kernel<<<T_TOK, 256, 0, stream>>>(Y4, pair2row, out);
}